// Round 5
// baseline (198.878 us; speedup 1.0000x reference)
//
#include <hip/hip_runtime.h>

// Problem constants
#define B_   16
#define C_   512
#define HW_  4096
#define M_   1024   // pooled positions (HW/4)
#define TPAD 136    // LDS epilogue row pad (ushorts): 272 B = 16B-aligned rows

typedef __attribute__((ext_vector_type(8))) short bf16x8;   // 8 bf16 = 4 VGPR
typedef __attribute__((ext_vector_type(4))) float f32x4;

static __device__ __forceinline__ unsigned short f2bf(float f) {
    union { float f; unsigned u; } v; v.f = f;
    unsigned r = v.u + 0x7fffu + ((v.u >> 16) & 1u);  // RNE
    return (unsigned short)(r >> 16);
}
static __device__ __forceinline__ float bf2f(unsigned short h) {
    union { unsigned u; float f; } v; v.u = ((unsigned)h) << 16;
    return v.f;
}
static __device__ __forceinline__ void gload_lds16(const void* g, void* l) {
    __builtin_amdgcn_global_load_lds(
        (const __attribute__((address_space(1))) unsigned int*)g,
        (__attribute__((address_space(3))) unsigned int*)l, 16, 0, 0);
}
// B-tile swizzle: takes all 8 values on write rows {4h+t} AND read rows {16n+l}
static __device__ __forceinline__ int fb(int row) { return (row ^ (row >> 2)) & 7; }

// ---------------------------------------------------------------------------
// K00: convert weights to bf16 + init g_p ones/zeros rows (256..271).
// Wb rows: [0,64) theta_w, [64,128) phi_w, [128,384) g_w. oWb = o_w [512][256].
__global__ __launch_bounds__(256) void k_weights(
    const float* __restrict__ thw, const float* __restrict__ phw,
    const float* __restrict__ gw,  const float* __restrict__ ow,
    unsigned short* __restrict__ Wb, unsigned short* __restrict__ oWb,
    unsigned short* __restrict__ g_p) {
    int i = blockIdx.x * 256 + threadIdx.x;
    if (i < 32768)        Wb[i] = f2bf(thw[i]);
    else if (i < 65536)   Wb[i] = f2bf(phw[i - 32768]);
    else if (i < 196608)  Wb[i] = f2bf(gw[i - 65536]);
    else if (i < 327680)  oWb[i - 196608] = f2bf(ow[i - 196608]);
    else if (i < 589824) {
        int i2 = i - 327680;          // [0, 262144): 16 b x 16 rows x 1024 m
        int b = i2 >> 14;
        int r = (i2 >> 10) & 15;      // row 256+r
        int m = i2 & 1023;
        g_p[((size_t)b * 272 + 256 + r) * M_ + m] =
            (r == 0) ? (unsigned short)0x3F80u : (unsigned short)0;
    }
}

// ---------------------------------------------------------------------------
// K1: projection GEMM per batch: P[384][4096] = Wb[384][512] @ x_b, reading x
// fp32 NATIVE layout (transpose fused into B-staging: reg 4x4 transpose +
// ds_write_b64, swizzle fb on both sides). A staged via global_load_lds
// (row&7 swizzle). FUSED epilogue: theta -> theta_n transposed; phi/g ->
// 2x2 maxpool -> phi_p / g_p. Each block covers 2 full H-rows.
__global__ __launch_bounds__(256, 4) void k_proj(
    const float* __restrict__ x, const unsigned short* __restrict__ Wb,
    unsigned short* __restrict__ theta_n, unsigned short* __restrict__ phi_p,
    unsigned short* __restrict__ g_p) {
    __shared__ unsigned short smem[128 * TPAD];   // 34,816 B; aliases As|Bs
    unsigned short* As = smem;                    // ushort idx [0, 8192)
    unsigned short* Bs = smem + 8192;             // ushort idx [8192, 16384)

    int b = blockIdx.z, mt = blockIdx.y, bx = blockIdx.x;
    int hw0 = bx * 128;
    int tid = threadIdx.x, w = tid >> 6, lane = tid & 63;
    int l15 = lane & 15, q = lane >> 4;
    int wr = w >> 1, wc = w & 1;

    const unsigned short* Ab = Wb + (size_t)(mt * 128) * 512;
    const float* xb = x + (size_t)b * C_ * HW_ + hw0;
    int trow = tid >> 3, tch = tid & 7;
    int hg4 = (tid & 31) * 4;                    // B-stage: local hw base
    int kq2 = (tid >> 5) * 2;                    // B-stage: k-group base

    f32x4 acc[4][4] = {};
    for (int ks = 0; ks < 8; ks++) {
        int k0 = ks * 64;
        if (ks) __syncthreads();
        // ---- stage A (weights, bf16): global_load_lds w16, row&7 swizzle
#pragma unroll
        for (int i = 0; i < 4; i++) {
            int row = i * 32 + trow;
            int ch = tch ^ (row & 7);
            gload_lds16(Ab + (size_t)row * 512 + k0 + ch * 8, &As[(i * 256 + w * 64) * 8]);
        }
        // ---- stage B (x fp32 -> bf16 transposed): reg 4x4 + ds_write_b64
#pragma unroll
        for (int it = 0; it < 2; it++) {
            int kg = kq2 + it;                   // 0..15: channels k0+kg*4..+4
            const float* xs = xb + (size_t)(k0 + kg * 4) * HW_ + hg4;
            float4 r0 = *reinterpret_cast<const float4*>(xs);
            float4 r1 = *reinterpret_cast<const float4*>(xs + HW_);
            float4 r2 = *reinterpret_cast<const float4*>(xs + 2 * HW_);
            float4 r3 = *reinterpret_cast<const float4*>(xs + 3 * HW_);
            const float* p0 = (const float*)&r0; const float* p1 = (const float*)&r1;
            const float* p2 = (const float*)&r2; const float* p3 = (const float*)&r3;
#pragma unroll
            for (int t = 0; t < 4; t++) {
                int row = hg4 + t;
                int ch = (kg >> 1) ^ fb(row);
                ushort4 u;
                u.x = f2bf(p0[t]); u.y = f2bf(p1[t]);
                u.z = f2bf(p2[t]); u.w = f2bf(p3[t]);
                *reinterpret_cast<ushort4*>(&Bs[row * 64 + ch * 8 + (kg & 1) * 4]) = u;
            }
        }
        __syncthreads();
#pragma unroll
        for (int kk = 0; kk < 2; kk++) {
            bf16x8 af[4], bfr[4];
#pragma unroll
            for (int mi = 0; mi < 4; mi++) {
                int row = wr * 64 + mi * 16 + l15;
                int ch = (kk * 4 + q) ^ (row & 7);
                af[mi] = *(const bf16x8*)&As[row * 64 + ch * 8];
            }
#pragma unroll
            for (int ni = 0; ni < 4; ni++) {
                int row = wc * 64 + ni * 16 + l15;
                int ch = (kk * 4 + q) ^ fb(row);
                bfr[ni] = *(const bf16x8*)&Bs[row * 64 + ch * 8];
            }
#pragma unroll
            for (int mi = 0; mi < 4; mi++)
#pragma unroll
                for (int ni = 0; ni < 4; ni++)
                    acc[mi][ni] = __builtin_amdgcn_mfma_f32_16x16x32_bf16(
                        af[mi], bfr[ni], acc[mi][ni], 0, 0, 0);
        }
    }

    // ---- epilogue: restage tile TRANSPOSED: smem[col(hw_l)][row(ch_l)], pad 136
    __syncthreads();
#pragma unroll
    for (int mi = 0; mi < 4; mi++)
#pragma unroll
        for (int ni = 0; ni < 4; ni++) {
            int col = wc * 64 + ni * 16 + l15;
            int row = wr * 64 + mi * 16 + q * 4;
            ushort4 u;
            u.x = f2bf(acc[mi][ni][0]); u.y = f2bf(acc[mi][ni][1]);
            u.z = f2bf(acc[mi][ni][2]); u.w = f2bf(acc[mi][ni][3]);
            *reinterpret_cast<ushort4*>(&smem[col * TPAD + row]) = u;
        }
    __syncthreads();

    if (mt == 0) {
        // theta rows 0..63 -> theta_n[b][hw][k]: thread t = 1 hw x 32 k, 64 B copy
        int hw_l = tid >> 1, kh = (tid & 1) * 32;
        const unsigned short* srcp = &smem[hw_l * TPAD + kh];
        unsigned short* dstp = theta_n + ((size_t)b * HW_ + hw0 + hw_l) * 64 + kh;
#pragma unroll
        for (int i = 0; i < 4; i++)
            *reinterpret_cast<uint4*>(dstp + i * 8) =
                *reinterpret_cast<const uint4*>(srcp + i * 8);
        // phi rows 64..127 -> pool -> phi_p[b][m][64]: thread = 8 m x 1 pc
        int pc = tid & 63, mg = tid >> 6;
#pragma unroll
        for (int j = 0; j < 8; j++) {
            int m_l = mg * 8 + j, w_ = m_l * 2;
            float v0 = bf2f(smem[(w_)      * TPAD + 64 + pc]);
            float v1 = bf2f(smem[(w_ + 1)  * TPAD + 64 + pc]);
            float v2 = bf2f(smem[(64 + w_) * TPAD + 64 + pc]);
            float v3 = bf2f(smem[(65 + w_) * TPAD + 64 + pc]);
            float v = fmaxf(fmaxf(v0, v1), fmaxf(v2, v3));
            phi_p[((size_t)b * M_ + bx * 32 + m_l) * 64 + pc] = f2bf(v);
        }
    } else {
        // g rows -> pool -> g_p[b][gc][1024]: thread = 1 gc x 16 m (32 B store)
        int lr = tid & 127, half = tid >> 7;
        int gc = (mt - 1) * 128 + lr;
        unsigned short* dst = g_p + ((size_t)b * 272 + gc) * M_ + bx * 32 + half * 16;
        unsigned short tmp[16];
#pragma unroll
        for (int i = 0; i < 16; i++) {
            int w_ = (half * 16 + i) * 2;
            float v0 = bf2f(smem[(w_)      * TPAD + lr]);
            float v1 = bf2f(smem[(w_ + 1)  * TPAD + lr]);
            float v2 = bf2f(smem[(64 + w_) * TPAD + lr]);
            float v3 = bf2f(smem[(65 + w_) * TPAD + lr]);
            tmp[i] = f2bf(fmaxf(fmaxf(v0, v1), fmaxf(v2, v3)));
        }
#pragma unroll
        for (int i = 0; i < 4; i++)
            *reinterpret_cast<ushort4*>(dst + i * 4) =
                *reinterpret_cast<const ushort4*>(&tmp[i * 4]);
    }
}

// ---------------------------------------------------------------------------
// K3: fused attention -> o_in [B][4096][256] bf16.
// Block = 512 threads (8 waves), 128 query rows (16/wave), batch b.
// Per m-chunk (64 cols): stage phi[64][64] + g[272][64] into LDS via
// global_load_lds w16, chunk-XOR-swizzled on the GLOBAL side (linear LDS dest),
// then S = theta@phi, P = exp(S) (no max-sub; logits bounded), O += P@g^T.
// Ones-row of g (row 256) accumulates the softmax denominator in acc[16].
__global__ __launch_bounds__(512, 4) void k_attn(
    const unsigned short* __restrict__ theta_n, const unsigned short* __restrict__ phi_p,
    const unsigned short* __restrict__ g_p, unsigned short* __restrict__ o_in) {
    __shared__ unsigned short phi_s[64 * 64];      //  8 KB, row=m, 8 chunks of 8 elem
    __shared__ unsigned short g_s[272 * 64];       // 34 KB, row=c
    __shared__ unsigned short p_lds[8][16][88];    // per-wave P tile [16n][64m]

    int b = blockIdx.y, n0 = blockIdx.x * 128;
    int tid = threadIdx.x, w = tid >> 6, lane = tid & 63;
    int l15 = lane & 15, q = lane >> 4;
    int nw = n0 + w * 16;

    // theta A-fragments (held all kernel): rows nw+l15, k = ks*32 + q*8 + [0..8)
    const unsigned short* th = theta_n + ((size_t)b * HW_ + nw + l15) * 64 + q * 8;
    bf16x8 a0 = *(const bf16x8*)(th);
    bf16x8 a1 = *(const bf16x8*)(th + 32);

    const unsigned short* phib = phi_p + (size_t)b * M_ * 64;
    const unsigned short* gb   = g_p   + (size_t)b * 272 * M_;

    int sw = l15 & 7;  // read-side XOR (row & 7 == l15 & 7 for all our rows)

    f32x4 acc[17] = {};  // 16 c-frags (c 0..255) + frag 16 = denominator column
    for (int mc = 0; mc < 16; mc++) {
        int m0 = mc * 64;
        __syncthreads();   // prior chunk's LDS reads complete before overwrite
        // ---- stage phi chunk: 8KB contiguous; 1 wave-issue per wave
        {
            int p = tid;                    // = w*64 + lane
            int row = p >> 3, ch = (p & 7) ^ (row & 7);
            gload_lds16(phib + (size_t)(m0 + row) * 64 + ch * 8, &phi_s[w * 512]);
        }
        // ---- stage g chunk: 34 segments of 1KB (8 rows each)
#pragma unroll
        for (int it = 0; it < 5; it++) {
            int s = w + it * 8;
            if (s < 34) {
                int row = s * 8 + (lane >> 3);
                int ch = (lane & 7) ^ (row & 7);
                gload_lds16(gb + (size_t)row * M_ + m0 + ch * 8, &g_s[s * 512]);
            }
        }
        __syncthreads();   // vmcnt(0) drain + barrier

        // ---- S phase: S[16n][64m] in 4 fragments, exp -> bf16 -> per-wave LDS
#pragma unroll
        for (int f = 0; f < 4; f++) {
            const unsigned short* pr = &phi_s[(f * 16 + l15) * 64];
            bf16x8 b0 = *(const bf16x8*)(pr + (q ^ sw) * 8);
            bf16x8 b1 = *(const bf16x8*)(pr + ((q + 4) ^ sw) * 8);
            f32x4 s = {};
            s = __builtin_amdgcn_mfma_f32_16x16x32_bf16(a0, b0, s, 0, 0, 0);
            s = __builtin_amdgcn_mfma_f32_16x16x32_bf16(a1, b1, s, 0, 0, 0);
#pragma unroll
            for (int j = 0; j < 4; j++)
                p_lds[w][q * 4 + j][f * 16 + l15] = f2bf(__expf(s[j]));
        }
        // ---- P A-fragments from LDS (same-wave dep; compiler inserts lgkmcnt)
        bf16x8 p0 = *(const bf16x8*)&p_lds[w][l15][q * 8];
        bf16x8 p1 = *(const bf16x8*)&p_lds[w][l15][32 + q * 8];
        // ---- O phase: acc[cf] += P[16n][64m] @ g^T[64m][16c]
#pragma unroll
        for (int cf = 0; cf < 17; cf++) {
            const unsigned short* gr = &g_s[(cf * 16 + l15) * 64];
            bf16x8 g0 = *(const bf16x8*)(gr + (q ^ sw) * 8);
            bf16x8 g1 = *(const bf16x8*)(gr + ((q + 4) ^ sw) * 8);
            acc[cf] = __builtin_amdgcn_mfma_f32_16x16x32_bf16(p0, g0, acc[cf], 0, 0, 0);
            acc[cf] = __builtin_amdgcn_mfma_f32_16x16x32_bf16(p1, g1, acc[cf], 0, 0, 0);
        }
    }

    // ---- epilogue: divide by denominator (frag 16, col 0 => lanes l15==0)
    float dinv[4];
#pragma unroll
    for (int j = 0; j < 4; j++) {
        float d = __shfl(acc[16][j], (lane & 48), 64);
        dinv[j] = 1.0f / d;
    }
#pragma unroll
    for (int cf = 0; cf < 16; cf++)
#pragma unroll
        for (int j = 0; j < 4; j++)
            o_in[((size_t)b * HW_ + nw + q * 4 + j) * 256 + cf * 16 + l15] =
                f2bf(acc[cf][j] * dinv[j]);
}

// ---------------------------------------------------------------------------
// K4: output projection + residual: out[b][cout][hw] = gamma * (o_in @ oW^T) + x
// m97 mainloop + LDS-restaged epilogue: tile -> smem[row][col] (pad 136),
// then 32-lane groups write 512 B contiguous float4 rows (x reads coalesced).
__global__ __launch_bounds__(256, 4) void k_oproj(
    const unsigned short* __restrict__ o_in, const unsigned short* __restrict__ oWb,
    const float* __restrict__ x, const float* __restrict__ gamma_p,
    float* __restrict__ out) {
    __shared__ unsigned short smem[128 * TPAD];   // 34,816 B; aliases As|Bs
    unsigned short* As = smem;
    unsigned short* Bs = smem + 8192;

    int b = blockIdx.z, mt = blockIdx.y, hw0 = blockIdx.x * 128;
    int tid = threadIdx.x, w = tid >> 6, lane = tid & 63;
    int l15 = lane & 15, q = lane >> 4;
    int wr = w >> 1, wc = w & 1;

    const unsigned short* Ab = oWb + (size_t)(mt * 128) * 256;
    const unsigned short* Bb = o_in + ((size_t)b * HW_ + hw0) * 256;
    int trow = tid >> 3, tch = tid & 7;

    f32x4 acc[4][4] = {};
    for (int ks = 0; ks < 4; ks++) {
        int k0 = ks * 64;
        if (ks) __syncthreads();
#pragma unroll
        for (int i = 0; i < 4; i++) {
            int row = i * 32 + trow;
            int ch = tch ^ (row & 7);
            gload_lds16(Ab + (size_t)row * 256 + k0 + ch * 8, &As[(i * 256 + w * 64) * 8]);
        }
#pragma unroll
        for (int i = 0; i < 4; i++) {
            int row = i * 32 + trow;
            int ch = tch ^ (row & 7);
            gload_lds16(Bb + (size_t)row * 256 + k0 + ch * 8, &Bs[(i * 256 + w * 64) * 8]);
        }
        __syncthreads();
#pragma unroll
        for (int kk = 0; kk < 2; kk++) {
            bf16x8 af[4], bfr[4];
#pragma unroll
            for (int mi = 0; mi < 4; mi++) {
                int row = wr * 64 + mi * 16 + l15;
                int ch = (kk * 4 + q) ^ (row & 7);
                af[mi] = *(const bf16x8*)&As[row * 64 + ch * 8];
            }
#pragma unroll
            for (int ni = 0; ni < 4; ni++) {
                int row = wc * 64 + ni * 16 + l15;
                int ch = (kk * 4 + q) ^ (row & 7);
                bfr[ni] = *(const bf16x8*)&Bs[row * 64 + ch * 8];
            }
#pragma unroll
            for (int mi = 0; mi < 4; mi++)
#pragma unroll
                for (int ni = 0; ni < 4; ni++)
                    acc[mi][ni] = __builtin_amdgcn_mfma_f32_16x16x32_bf16(
                        af[mi], bfr[ni], acc[mi][ni], 0, 0, 0);
        }
    }

    // ---- epilogue: restage row-major smem[row(cout_l)][col(hw_l)], pad 136
    __syncthreads();
#pragma unroll
    for (int mi = 0; mi < 4; mi++)
#pragma unroll
        for (int ni = 0; ni < 4; ni++) {
            int col = wc * 64 + ni * 16 + l15;
            int rb = wr * 64 + mi * 16 + q * 4;
#pragma unroll
            for (int j = 0; j < 4; j++)
                smem[(rb + j) * TPAD + col] = f2bf(acc[mi][ni][j]);
        }
    __syncthreads();

    float gam = *gamma_p;
    int sub = tid >> 5, p32 = tid & 31;
#pragma unroll
    for (int p = 0; p < 16; p++) {
        int row = p * 8 + sub;
        ushort4 v = *reinterpret_cast<const ushort4*>(&smem[row * TPAD + p32 * 4]);
        size_t idx = ((size_t)b * C_ + mt * 128 + row) * HW_ + hw0 + p32 * 4;
        float4 xv = *reinterpret_cast<const float4*>(x + idx);
        float4 o;
        o.x = gam * bf2f(v.x) + xv.x;
        o.y = gam * bf2f(v.y) + xv.y;
        o.z = gam * bf2f(v.z) + xv.z;
        o.w = gam * bf2f(v.w) + xv.w;
        *reinterpret_cast<float4*>(out + idx) = o;
    }
}

// ---------------------------------------------------------------------------
extern "C" void kernel_launch(void* const* d_in, const int* in_sizes, int n_in,
                              void* d_out, int out_size, void* d_ws, size_t ws_size,
                              hipStream_t stream) {
    const float* x     = (const float*)d_in[0];
    const float* thw   = (const float*)d_in[1];
    const float* phw   = (const float*)d_in[2];
    const float* gw    = (const float*)d_in[3];
    const float* ow    = (const float*)d_in[4];
    const float* gamma = (const float*)d_in[5];
    float* out = (float*)d_out;

    char* ws = (char*)d_ws;
    // workspace layout (bytes), all 256-aligned; total 53,608,448
    unsigned short* Wb   = (unsigned short*)(ws + 0);          //     393,216
    unsigned short* oWb  = (unsigned short*)(ws + 393216);     //     262,144
    unsigned short* oin  = (unsigned short*)(ws + 655360);     //  33,554,432
    unsigned short* thn  = (unsigned short*)(ws + 34209792);   //   8,388,608
    unsigned short* phip = (unsigned short*)(ws + 42598400);   //   2,097,152
    unsigned short* gp   = (unsigned short*)(ws + 44695552);   //   8,912,896

    hipLaunchKernelGGL(k_weights, dim3(2304), dim3(256), 0, stream, thw, phw, gw, ow, Wb, oWb, gp);
    hipLaunchKernelGGL(k_proj, dim3(32, 3, 16), dim3(256), 0, stream, x, Wb, thn, phip, gp);
    hipLaunchKernelGGL(k_attn, dim3(32, 16), dim3(512), 0, stream, thn, phip, gp, oin);
    hipLaunchKernelGGL(k_oproj, dim3(32, 4, 16), dim3(256), 0, stream, oin, oWb, x, gamma, out);
}

// Round 6
// 189.134 us; speedup vs baseline: 1.0515x; 1.0515x over previous
//
#include <hip/hip_runtime.h>

// Problem constants
#define B_   16
#define C_   512
#define HW_  4096
#define M_   1024   // pooled positions (HW/4)
#define TPAD 136    // LDS epilogue row pad (ushorts): 272 B = 16B-aligned rows

typedef __attribute__((ext_vector_type(8))) short bf16x8;   // 8 bf16 = 4 VGPR
typedef __attribute__((ext_vector_type(4))) float f32x4;

static __device__ __forceinline__ unsigned short f2bf(float f) {
    union { float f; unsigned u; } v; v.f = f;
    unsigned r = v.u + 0x7fffu + ((v.u >> 16) & 1u);  // RNE
    return (unsigned short)(r >> 16);
}
static __device__ __forceinline__ float bf2f(unsigned short h) {
    union { unsigned u; float f; } v; v.u = ((unsigned)h) << 16;
    return v.f;
}
static __device__ __forceinline__ void gload_lds16(const void* g, void* l) {
    __builtin_amdgcn_global_load_lds(
        (const __attribute__((address_space(1))) unsigned int*)g,
        (__attribute__((address_space(3))) unsigned int*)l, 16, 0, 0);
}
// B-tile swizzle: takes all 8 values on write rows {4h+t} AND read rows {16n+l}
static __device__ __forceinline__ int fb(int row) { return (row ^ (row >> 2)) & 7; }

// ---------------------------------------------------------------------------
// K00: convert weights to bf16 + init g_p ones/zeros rows (256..271).
// Wb rows: [0,64) theta_w, [64,128) phi_w, [128,384) g_w. oWb = o_w [512][256].
__global__ __launch_bounds__(256) void k_weights(
    const float* __restrict__ thw, const float* __restrict__ phw,
    const float* __restrict__ gw,  const float* __restrict__ ow,
    unsigned short* __restrict__ Wb, unsigned short* __restrict__ oWb,
    unsigned short* __restrict__ g_p) {
    int i = blockIdx.x * 256 + threadIdx.x;
    if (i < 32768)        Wb[i] = f2bf(thw[i]);
    else if (i < 65536)   Wb[i] = f2bf(phw[i - 32768]);
    else if (i < 196608)  Wb[i] = f2bf(gw[i - 65536]);
    else if (i < 327680)  oWb[i - 196608] = f2bf(ow[i - 196608]);
    else if (i < 589824) {
        int i2 = i - 327680;          // [0, 262144): 16 b x 16 rows x 1024 m
        int b = i2 >> 14;
        int r = (i2 >> 10) & 15;      // row 256+r
        int m = i2 & 1023;
        g_p[((size_t)b * 272 + 256 + r) * M_ + m] =
            (r == 0) ? (unsigned short)0x3F80u : (unsigned short)0;
    }
}

// ---------------------------------------------------------------------------
// K1: projection GEMM per batch: P[384][4096] = Wb[384][512] @ x_b, reading x
// fp32 NATIVE layout. Pipelined: B (x, transposed in regs) double-buffered in
// LDS with next-step loads issued before the MFMA phase; A (weights, L2-hot)
// read directly global->VGPR. One barrier per k-step. FUSED epilogue: theta ->
// theta_n transposed; phi/g -> 2x2 maxpool -> phi_p / g_p.
__global__ __launch_bounds__(256, 2) void k_proj(
    const float* __restrict__ x, const unsigned short* __restrict__ Wb,
    unsigned short* __restrict__ theta_n, unsigned short* __restrict__ phi_p,
    unsigned short* __restrict__ g_p) {
    __shared__ unsigned short smem[128 * TPAD];   // 34,816 B; aliases Bs0|Bs1
    unsigned short* Bs0 = smem;                   // ushort idx [0, 8192)
    unsigned short* Bs1 = smem + 8192;            // ushort idx [8192, 16384)

    int b = blockIdx.z, mt = blockIdx.y, bx = blockIdx.x;
    int hw0 = bx * 128;
    int tid = threadIdx.x, w = tid >> 6, lane = tid & 63;
    int l15 = lane & 15, q = lane >> 4;
    int wr = w >> 1, wc = w & 1;

    const unsigned short* Ab = Wb + (size_t)(mt * 128) * 512;
    const float* xb = x + (size_t)b * C_ * HW_ + hw0;
    int hg4 = (tid & 31) * 4;                    // B-stage: local hw base (4 rows)
    int kq2 = (tid >> 5) * 2;                    // B-stage: k-group base (2 kg)

    float4 breg[8];                              // 2 kg x 4 hw-rows of float4

#define LOADB(k0v)                                                             \
    _Pragma("unroll")                                                          \
    for (int it = 0; it < 2; it++) {                                           \
        int kg = kq2 + it;                                                     \
        const float* xs = xb + (size_t)((k0v) + kg * 4) * HW_ + hg4;           \
        breg[it * 4 + 0] = *reinterpret_cast<const float4*>(xs);               \
        breg[it * 4 + 1] = *reinterpret_cast<const float4*>(xs + HW_);         \
        breg[it * 4 + 2] = *reinterpret_cast<const float4*>(xs + 2 * HW_);     \
        breg[it * 4 + 3] = *reinterpret_cast<const float4*>(xs + 3 * HW_);     \
    }

#define WRITEB(dst)                                                            \
    _Pragma("unroll")                                                          \
    for (int it = 0; it < 2; it++) {                                           \
        int kg = kq2 + it;                                                     \
        _Pragma("unroll")                                                      \
        for (int t = 0; t < 4; t++) {                                          \
            int row = hg4 + t;                                                 \
            int ch = (kg >> 1) ^ fb(row);                                      \
            ushort4 u;                                                         \
            u.x = f2bf(((const float*)&breg[it * 4 + 0])[t]);                  \
            u.y = f2bf(((const float*)&breg[it * 4 + 1])[t]);                  \
            u.z = f2bf(((const float*)&breg[it * 4 + 2])[t]);                  \
            u.w = f2bf(((const float*)&breg[it * 4 + 3])[t]);                  \
            *reinterpret_cast<ushort4*>(&(dst)[row * 64 + ch * 8 + (kg & 1) * 4]) = u; \
        }                                                                      \
    }

    // prologue: stage k-step 0 into Bs0
    LOADB(0);
    WRITEB(Bs0);

    f32x4 acc[4][4] = {};
#pragma unroll
    for (int ks = 0; ks < 8; ks++) {
        int k0 = ks * 64;
        unsigned short* cur = (ks & 1) ? Bs1 : Bs0;
        unsigned short* nxt = (ks & 1) ? Bs0 : Bs1;
        __syncthreads();               // cur fully written (prev iter / prologue)
        // ---- A fragments direct from global (Wb is L2-resident), issued first
        bf16x8 af[2][4];
#pragma unroll
        for (int kk = 0; kk < 2; kk++)
#pragma unroll
            for (int mi = 0; mi < 4; mi++) {
                int row = wr * 64 + mi * 16 + l15;
                af[kk][mi] = *(const bf16x8*)(Ab + (size_t)row * 512 + k0 + kk * 32 + q * 8);
            }
        // ---- issue next k-step's x loads (fly during MFMA phase)
        if (ks < 7) { LOADB(k0 + 64); }
        // ---- MFMA on cur
#pragma unroll
        for (int kk = 0; kk < 2; kk++) {
            bf16x8 bfr[4];
#pragma unroll
            for (int ni = 0; ni < 4; ni++) {
                int row = wc * 64 + ni * 16 + l15;
                int ch = (kk * 4 + q) ^ fb(row);
                bfr[ni] = *(const bf16x8*)&cur[row * 64 + ch * 8];
            }
#pragma unroll
            for (int mi = 0; mi < 4; mi++)
#pragma unroll
                for (int ni = 0; ni < 4; ni++)
                    acc[mi][ni] = __builtin_amdgcn_mfma_f32_16x16x32_bf16(
                        af[kk][mi], bfr[ni], acc[mi][ni], 0, 0, 0);
        }
        // ---- write next buffer (vmcnt-waits only on this iter's x loads)
        if (ks < 7) { WRITEB(nxt); }
    }
#undef LOADB
#undef WRITEB

    // ---- epilogue: restage tile TRANSPOSED: smem[col(hw_l)][row(ch_l)], pad 136
    __syncthreads();
#pragma unroll
    for (int mi = 0; mi < 4; mi++)
#pragma unroll
        for (int ni = 0; ni < 4; ni++) {
            int col = wc * 64 + ni * 16 + l15;
            int row = wr * 64 + mi * 16 + q * 4;
            ushort4 u;
            u.x = f2bf(acc[mi][ni][0]); u.y = f2bf(acc[mi][ni][1]);
            u.z = f2bf(acc[mi][ni][2]); u.w = f2bf(acc[mi][ni][3]);
            *reinterpret_cast<ushort4*>(&smem[col * TPAD + row]) = u;
        }
    __syncthreads();

    if (mt == 0) {
        // theta rows 0..63 -> theta_n[b][hw][k]: thread t = 1 hw x 32 k, 64 B copy
        int hw_l = tid >> 1, kh = (tid & 1) * 32;
        const unsigned short* srcp = &smem[hw_l * TPAD + kh];
        unsigned short* dstp = theta_n + ((size_t)b * HW_ + hw0 + hw_l) * 64 + kh;
#pragma unroll
        for (int i = 0; i < 4; i++)
            *reinterpret_cast<uint4*>(dstp + i * 8) =
                *reinterpret_cast<const uint4*>(srcp + i * 8);
        // phi rows 64..127 -> pool -> phi_p[b][m][64]: thread = 8 m x 1 pc
        int pc = tid & 63, mg = tid >> 6;
#pragma unroll
        for (int j = 0; j < 8; j++) {
            int m_l = mg * 8 + j, w_ = m_l * 2;
            float v0 = bf2f(smem[(w_)      * TPAD + 64 + pc]);
            float v1 = bf2f(smem[(w_ + 1)  * TPAD + 64 + pc]);
            float v2 = bf2f(smem[(64 + w_) * TPAD + 64 + pc]);
            float v3 = bf2f(smem[(65 + w_) * TPAD + 64 + pc]);
            float v = fmaxf(fmaxf(v0, v1), fmaxf(v2, v3));
            phi_p[((size_t)b * M_ + bx * 32 + m_l) * 64 + pc] = f2bf(v);
        }
    } else {
        // g rows -> pool -> g_p[b][gc][1024]: thread = 1 gc x 16 m (32 B store)
        int lr = tid & 127, half = tid >> 7;
        int gc = (mt - 1) * 128 + lr;
        unsigned short* dst = g_p + ((size_t)b * 272 + gc) * M_ + bx * 32 + half * 16;
        unsigned short tmp[16];
#pragma unroll
        for (int i = 0; i < 16; i++) {
            int w_ = (half * 16 + i) * 2;
            float v0 = bf2f(smem[(w_)      * TPAD + lr]);
            float v1 = bf2f(smem[(w_ + 1)  * TPAD + lr]);
            float v2 = bf2f(smem[(64 + w_) * TPAD + lr]);
            float v3 = bf2f(smem[(65 + w_) * TPAD + lr]);
            tmp[i] = f2bf(fmaxf(fmaxf(v0, v1), fmaxf(v2, v3)));
        }
#pragma unroll
        for (int i = 0; i < 4; i++)
            *reinterpret_cast<ushort4*>(dst + i * 4) =
                *reinterpret_cast<const ushort4*>(&tmp[i * 4]);
    }
}

// ---------------------------------------------------------------------------
// K3: fused attention -> o_in [B][4096][256] bf16.
// Block = 512 threads (8 waves), 128 query rows (16/wave), batch b.
// Per m-chunk (64 cols): stage phi[64][64] + g[272][64] into LDS via
// global_load_lds w16, chunk-XOR-swizzled on the GLOBAL side (linear LDS dest),
// then S = theta@phi, P = exp(S) (no max-sub; logits bounded), O += P@g^T.
// Ones-row of g (row 256) accumulates the softmax denominator in acc[16].
__global__ __launch_bounds__(512, 4) void k_attn(
    const unsigned short* __restrict__ theta_n, const unsigned short* __restrict__ phi_p,
    const unsigned short* __restrict__ g_p, unsigned short* __restrict__ o_in) {
    __shared__ unsigned short phi_s[64 * 64];      //  8 KB, row=m, 8 chunks of 8 elem
    __shared__ unsigned short g_s[272 * 64];       // 34 KB, row=c
    __shared__ unsigned short p_lds[8][16][88];    // per-wave P tile [16n][64m]

    int b = blockIdx.y, n0 = blockIdx.x * 128;
    int tid = threadIdx.x, w = tid >> 6, lane = tid & 63;
    int l15 = lane & 15, q = lane >> 4;
    int nw = n0 + w * 16;

    // theta A-fragments (held all kernel): rows nw+l15, k = ks*32 + q*8 + [0..8)
    const unsigned short* th = theta_n + ((size_t)b * HW_ + nw + l15) * 64 + q * 8;
    bf16x8 a0 = *(const bf16x8*)(th);
    bf16x8 a1 = *(const bf16x8*)(th + 32);

    const unsigned short* phib = phi_p + (size_t)b * M_ * 64;
    const unsigned short* gb   = g_p   + (size_t)b * 272 * M_;

    int sw = l15 & 7;  // read-side XOR (row & 7 == l15 & 7 for all our rows)

    f32x4 acc[17] = {};  // 16 c-frags (c 0..255) + frag 16 = denominator column
    for (int mc = 0; mc < 16; mc++) {
        int m0 = mc * 64;
        __syncthreads();   // prior chunk's LDS reads complete before overwrite
        // ---- stage phi chunk: 8KB contiguous; 1 wave-issue per wave
        {
            int p = tid;                    // = w*64 + lane
            int row = p >> 3, ch = (p & 7) ^ (row & 7);
            gload_lds16(phib + (size_t)(m0 + row) * 64 + ch * 8, &phi_s[w * 512]);
        }
        // ---- stage g chunk: 34 segments of 1KB (8 rows each)
#pragma unroll
        for (int it = 0; it < 5; it++) {
            int s = w + it * 8;
            if (s < 34) {
                int row = s * 8 + (lane >> 3);
                int ch = (lane & 7) ^ (row & 7);
                gload_lds16(gb + (size_t)row * M_ + m0 + ch * 8, &g_s[s * 512]);
            }
        }
        __syncthreads();   // vmcnt(0) drain + barrier

        // ---- S phase: S[16n][64m] in 4 fragments, exp -> bf16 -> per-wave LDS
#pragma unroll
        for (int f = 0; f < 4; f++) {
            const unsigned short* pr = &phi_s[(f * 16 + l15) * 64];
            bf16x8 b0 = *(const bf16x8*)(pr + (q ^ sw) * 8);
            bf16x8 b1 = *(const bf16x8*)(pr + ((q + 4) ^ sw) * 8);
            f32x4 s = {};
            s = __builtin_amdgcn_mfma_f32_16x16x32_bf16(a0, b0, s, 0, 0, 0);
            s = __builtin_amdgcn_mfma_f32_16x16x32_bf16(a1, b1, s, 0, 0, 0);
#pragma unroll
            for (int j = 0; j < 4; j++)
                p_lds[w][q * 4 + j][f * 16 + l15] = f2bf(__expf(s[j]));
        }
        // ---- P A-fragments from LDS (same-wave dep; compiler inserts lgkmcnt)
        bf16x8 p0 = *(const bf16x8*)&p_lds[w][l15][q * 8];
        bf16x8 p1 = *(const bf16x8*)&p_lds[w][l15][32 + q * 8];
        // ---- O phase: acc[cf] += P[16n][64m] @ g^T[64m][16c]
#pragma unroll
        for (int cf = 0; cf < 17; cf++) {
            const unsigned short* gr = &g_s[(cf * 16 + l15) * 64];
            bf16x8 g0 = *(const bf16x8*)(gr + (q ^ sw) * 8);
            bf16x8 g1 = *(const bf16x8*)(gr + ((q + 4) ^ sw) * 8);
            acc[cf] = __builtin_amdgcn_mfma_f32_16x16x32_bf16(p0, g0, acc[cf], 0, 0, 0);
            acc[cf] = __builtin_amdgcn_mfma_f32_16x16x32_bf16(p1, g1, acc[cf], 0, 0, 0);
        }
    }

    // ---- epilogue: divide by denominator (frag 16, col 0 => lanes l15==0)
    float dinv[4];
#pragma unroll
    for (int j = 0; j < 4; j++) {
        float d = __shfl(acc[16][j], (lane & 48), 64);
        dinv[j] = 1.0f / d;
    }
#pragma unroll
    for (int cf = 0; cf < 16; cf++)
#pragma unroll
        for (int j = 0; j < 4; j++)
            o_in[((size_t)b * HW_ + nw + q * 4 + j) * 256 + cf * 16 + l15] =
                f2bf(acc[cf][j] * dinv[j]);
}

// ---------------------------------------------------------------------------
// K4: output projection + residual: out[b][cout][hw] = gamma * (o_in @ oW^T) + x
// m97 mainloop + LDS-restaged epilogue: tile -> smem[row][col] (pad 136),
// then 32-lane groups write 512 B contiguous float4 rows (x reads coalesced).
__global__ __launch_bounds__(256, 4) void k_oproj(
    const unsigned short* __restrict__ o_in, const unsigned short* __restrict__ oWb,
    const float* __restrict__ x, const float* __restrict__ gamma_p,
    float* __restrict__ out) {
    __shared__ unsigned short smem[128 * TPAD];   // 34,816 B; aliases As|Bs
    unsigned short* As = smem;
    unsigned short* Bs = smem + 8192;

    int b = blockIdx.z, mt = blockIdx.y, hw0 = blockIdx.x * 128;
    int tid = threadIdx.x, w = tid >> 6, lane = tid & 63;
    int l15 = lane & 15, q = lane >> 4;
    int wr = w >> 1, wc = w & 1;

    const unsigned short* Ab = oWb + (size_t)(mt * 128) * 256;
    const unsigned short* Bb = o_in + ((size_t)b * HW_ + hw0) * 256;
    int trow = tid >> 3, tch = tid & 7;

    f32x4 acc[4][4] = {};
    for (int ks = 0; ks < 4; ks++) {
        int k0 = ks * 64;
        if (ks) __syncthreads();
#pragma unroll
        for (int i = 0; i < 4; i++) {
            int row = i * 32 + trow;
            int ch = tch ^ (row & 7);
            gload_lds16(Ab + (size_t)row * 256 + k0 + ch * 8, &As[(i * 256 + w * 64) * 8]);
        }
#pragma unroll
        for (int i = 0; i < 4; i++) {
            int row = i * 32 + trow;
            int ch = tch ^ (row & 7);
            gload_lds16(Bb + (size_t)row * 256 + k0 + ch * 8, &Bs[(i * 256 + w * 64) * 8]);
        }
        __syncthreads();
#pragma unroll
        for (int kk = 0; kk < 2; kk++) {
            bf16x8 af[4], bfr[4];
#pragma unroll
            for (int mi = 0; mi < 4; mi++) {
                int row = wr * 64 + mi * 16 + l15;
                int ch = (kk * 4 + q) ^ (row & 7);
                af[mi] = *(const bf16x8*)&As[row * 64 + ch * 8];
            }
#pragma unroll
            for (int ni = 0; ni < 4; ni++) {
                int row = wc * 64 + ni * 16 + l15;
                int ch = (kk * 4 + q) ^ (row & 7);
                bfr[ni] = *(const bf16x8*)&Bs[row * 64 + ch * 8];
            }
#pragma unroll
            for (int mi = 0; mi < 4; mi++)
#pragma unroll
                for (int ni = 0; ni < 4; ni++)
                    acc[mi][ni] = __builtin_amdgcn_mfma_f32_16x16x32_bf16(
                        af[mi], bfr[ni], acc[mi][ni], 0, 0, 0);
        }
    }

    // ---- epilogue: restage row-major smem[row(cout_l)][col(hw_l)], pad 136
    __syncthreads();
#pragma unroll
    for (int mi = 0; mi < 4; mi++)
#pragma unroll
        for (int ni = 0; ni < 4; ni++) {
            int col = wc * 64 + ni * 16 + l15;
            int rb = wr * 64 + mi * 16 + q * 4;
#pragma unroll
            for (int j = 0; j < 4; j++)
                smem[(rb + j) * TPAD + col] = f2bf(acc[mi][ni][j]);
        }
    __syncthreads();

    float gam = *gamma_p;
    int sub = tid >> 5, p32 = tid & 31;
#pragma unroll
    for (int p = 0; p < 16; p++) {
        int row = p * 8 + sub;
        ushort4 v = *reinterpret_cast<const ushort4*>(&smem[row * TPAD + p32 * 4]);
        size_t idx = ((size_t)b * C_ + mt * 128 + row) * HW_ + hw0 + p32 * 4;
        float4 xv = *reinterpret_cast<const float4*>(x + idx);
        float4 o;
        o.x = gam * bf2f(v.x) + xv.x;
        o.y = gam * bf2f(v.y) + xv.y;
        o.z = gam * bf2f(v.z) + xv.z;
        o.w = gam * bf2f(v.w) + xv.w;
        *reinterpret_cast<float4*>(out + idx) = o;
    }
}

// ---------------------------------------------------------------------------
extern "C" void kernel_launch(void* const* d_in, const int* in_sizes, int n_in,
                              void* d_out, int out_size, void* d_ws, size_t ws_size,
                              hipStream_t stream) {
    const float* x     = (const float*)d_in[0];
    const float* thw   = (const float*)d_in[1];
    const float* phw   = (const float*)d_in[2];
    const float* gw    = (const float*)d_in[3];
    const float* ow    = (const float*)d_in[4];
    const float* gamma = (const float*)d_in[5];
    float* out = (float*)d_out;

    char* ws = (char*)d_ws;
    // workspace layout (bytes), all 256-aligned; total 53,608,448
    unsigned short* Wb   = (unsigned short*)(ws + 0);          //     393,216
    unsigned short* oWb  = (unsigned short*)(ws + 393216);     //     262,144
    unsigned short* oin  = (unsigned short*)(ws + 655360);     //  33,554,432
    unsigned short* thn  = (unsigned short*)(ws + 34209792);   //   8,388,608
    unsigned short* phip = (unsigned short*)(ws + 42598400);   //   2,097,152
    unsigned short* gp   = (unsigned short*)(ws + 44695552);   //   8,912,896

    hipLaunchKernelGGL(k_weights, dim3(2304), dim3(256), 0, stream, thw, phw, gw, ow, Wb, oWb, gp);
    hipLaunchKernelGGL(k_proj, dim3(32, 3, 16), dim3(256), 0, stream, x, Wb, thn, phip, gp);
    hipLaunchKernelGGL(k_attn, dim3(32, 16), dim3(512), 0, stream, thn, phip, gp, oin);
    hipLaunchKernelGGL(k_oproj, dim3(32, 4, 16), dim3(256), 0, stream, oin, oWb, x, gamma, out);
}